// Round 12
// baseline (328.935 us; speedup 1.0000x reference)
//
#include <hip/hip_runtime.h>

// Problem constants (N=64, D=64, H=64, W=64, K=512)
#define VQ_D   64
#define VQ_K   512
#define VQ_HW  4096
#define VQ_M   262144
#define VQ_LOSS_OFF 16777216
#define VQ_IDX_OFF  16777217

// Flat margin for the fallback path only. The fast path uses a per-point
// adaptive margin: eps = 2*ulp(t_ub) + 1.6e-5, where t_ub bounds zsq+esq.
// Derivation: ref dist d = fl(fl(zsq+esq) - fl(2dot)) carries two mag-t
// roundings (each <= ulp(t)/2 ... total <= ulp(t) per d, 2*ulp(t) per pair);
// approx-vs-ref dot error |2acc - fl(2dot_ref)| <= 7.6e-6 (bf16 hi/lo
// residues <= 2^-18|z||e|, dropped zl*el <= 2^-16|z||e|, MFMA fp32
// accumulation, ref chain rounding), doubled = 1.5e-5 <= C = 1.6e-5.
// Rescued points are recomputed with the bitwise reference path, so the
// margin affects speed only, never output.
#define VQ_EPS  1e-4f

// Fast-path workspace layout (bytes):
//   [0,8)    double loss accumulator
//   [8,12)   int rescue-list counter
//   [12,2060) float esq[512]
//   [2060, 2060+4*VQ_M) int rescue list
#define WS_CNT_OFF  8
#define WS_ESQ_OFF  12
#define WS_LIST_OFF 2060
#define WS_NEED     (2060 + 4 * VQ_M)

typedef float  f32x4  __attribute__((ext_vector_type(4)));
typedef short  bf16x8 __attribute__((ext_vector_type(8)));

__device__ __forceinline__ unsigned short f2bf_rne(float f) {
    unsigned u = __float_as_uint(f);
    u += 0x7FFFu + ((u >> 16) & 1u);
    return (unsigned short)(u >> 16);
}
__device__ __forceinline__ float bf2f(unsigned short h) {
    return __uint_as_float(((unsigned)h) << 16);
}
// LDS fragment-slot byte offset with bank swizzle (involution on write+read).
__device__ __forceinline__ int ldx(int slot) {
    return (slot << 4) ^ (((slot >> 4) & 3) << 4);
}

// ---------------------------------------------------------------------------
// Kernel 1: e_sq[k] = sum_d emb[k][d]^2 (numpy pairwise, n=64 path).
// ---------------------------------------------------------------------------
__global__ void vq_prep(const float* __restrict__ emb, float* __restrict__ esq) {
#pragma clang fp contract(off)
    int k = blockIdx.x * 256 + threadIdx.x;
    if (k < VQ_K) {
        const float* e = emb + k * VQ_D;
        float p[VQ_D];
#pragma unroll
        for (int d = 0; d < VQ_D; ++d) p[d] = e[d] * e[d];
        float r[8];
#pragma unroll
        for (int j = 0; j < 8; ++j) r[j] = p[j];
#pragma unroll
        for (int i = 8; i < VQ_D; i += 8)
#pragma unroll
            for (int j = 0; j < 8; ++j) r[j] += p[i + j];
        esq[k] = ((r[0] + r[1]) + (r[2] + r[3])) + ((r[4] + r[5]) + (r[6] + r[7]));
    }
}

// ---------------------------------------------------------------------------
// Shared device helper (fallback path): wave-cooperative EXACT argmin,
// codebook from L2. Bitwise reference path; lexicographic (dist,k) reduce.
// ---------------------------------------------------------------------------
__device__ __forceinline__ int vq_exact_point(
        const float* __restrict__ zr,      // wave-uniform &z[n][0][hw]
        const float* __restrict__ emb,
        const float* __restrict__ esq,     // any source w/ identical bits
        int lane)
{
    float r8[8];
#pragma unroll
    for (int dj = 0; dj < 8; ++dj) {
        float f = zr[(size_t)dj * 4096];
        r8[dj] = f * f;
    }
#pragma unroll
    for (int i = 8; i < 64; i += 8)
#pragma unroll
        for (int dj = 0; dj < 8; ++dj) {
            float f = zr[(size_t)(i + dj) * 4096];
            r8[dj] += f * f;
        }
    const float zsq = ((r8[0] + r8[1]) + (r8[2] + r8[3]))
                    + ((r8[4] + r8[5]) + (r8[6] + r8[7]));
    float a[8];
#pragma unroll
    for (int q = 0; q < 8; ++q) a[q] = 0.f;
    const float* er0 = emb + (size_t)(lane * 8) * VQ_D;
    for (int c4 = 0; c4 < 16; ++c4) {
        f32x4 z4;
#pragma unroll
        for (int x = 0; x < 4; ++x) z4[x] = zr[(size_t)(c4 * 4 + x) * 4096];
#pragma unroll
        for (int q = 0; q < 8; ++q) {
            f32x4 e4 = *(const f32x4*)(er0 + q * VQ_D + c4 * 4);
#pragma unroll
            for (int x = 0; x < 4; ++x)
                a[q] = __builtin_fmaf(z4[x], e4[x], a[q]);
        }
    }
    float fb = 3.4e38f; int fk = 0;
#pragma unroll
    for (int q = 0; q < 8; ++q) {                // k ascending within lane
        const int kk = lane * 8 + q;
        float tt = zsq + esq[kk];
        float dd = tt - 2.0f * a[q];
        if (dd < fb) { fb = dd; fk = kk; }       // strict <: first occurrence
    }
#pragma unroll
    for (int off = 32; off > 0; off >>= 1) {     // lexicographic (dist, k)
        float ob = __shfl_xor(fb, off, 64);
        int   ok = __shfl_xor(fk, off, 64);
        if (ob < fb || (ob == fb && ok < fk)) { fb = ob; fk = ok; }
    }
    return fk;
}

// ---------------------------------------------------------------------------
// Kernel 2 (fast path): MFMA argmin, provisional idx + ambiguous-list
// append with PER-POINT adaptive margin. Uniform block duration (no inline
// rescue). 8 LDS phases x 64 rows (18.4 KB); launch_bounds(256,4) -> VGPR
// ~66, no spills (R10's (256,8) forced 32 VGPR and spilled 3 GB).
// ---------------------------------------------------------------------------
__global__ __launch_bounds__(256, 4) void vq_main_fast(
        const float* __restrict__ z_e,
        const float* __restrict__ emb,
        const float* __restrict__ esq,
        float* __restrict__ out,
        int* __restrict__ cnt_p,
        int* __restrict__ list)
{
#pragma clang fp contract(off)
    __shared__ __align__(16) char lbh[8192];    // one phase (64 rows), hi
    __shared__ __align__(16) char lbl[8192];    // one phase, lo
    __shared__ float lesq[512];

    const int tid  = threadIdx.x;
    const int wave = tid >> 6, lane = tid & 63;
    const int c15  = lane & 15, g = lane >> 4;

    lesq[tid]       = esq[tid];
    lesq[tid + 256] = esq[tid + 256];

    const int mblk = blockIdx.x * 128;               // block's first point
    const int n    = mblk >> 12;                     // all 128 pts in one n
    const int hwb  = (mblk & 4095) + wave * 32;      // wave's first hw
    const float* zn = z_e + (size_t)n * 262144;

    // ---- A fragments: z hi/lo for 2 m-subtiles x 2 k-halves, plus a
    //      per-point zsq upper-bound estimate (for the adaptive margin) ----
    bf16x8 ah[2][2], al[2][2];
    float zsq_est[2];
#pragma unroll
    for (int ms = 0; ms < 2; ++ms) {
        const int hw = hwb + ms * 16 + c15;
        float sq = 0.f;
#pragma unroll
        for (int s = 0; s < 2; ++s) {
#pragma unroll
            for (int e = 0; e < 8; ++e) {
                const int d = 32 * s + 8 * g + e;
                float f = zn[(size_t)d * 4096 + hw];
                sq = __builtin_fmaf(f, f, sq);
                unsigned short h = f2bf_rne(f);
                ah[ms][s][e] = (short)h;
                al[ms][s][e] = (short)f2bf_rne(f - bf2f(h));
            }
        }
        sq += __shfl_xor(sq, 16, 64);                // reduce over g
        sq += __shfl_xor(sq, 32, 64);
        zsq_est[ms] = sq;                            // all g-lanes of col c15
    }

    float best[2][4], sec[2][4];
    int   bidx[2][4];
#pragma unroll
    for (int ms = 0; ms < 2; ++ms)
#pragma unroll
        for (int r = 0; r < 4; ++r) {
            best[ms][r] = 3.4e38f; sec[ms][r] = 3.4e38f; bidx[ms][r] = 0;
        }

    // ---- scan K in eight LDS phases of 64 rows ----
    for (int ph = 0; ph < 8; ++ph) {
        __syncthreads();                             // prior readers done
#pragma unroll
        for (int j = 0; j < 2; ++j) {
            const int f8  = j * 256 + tid;           // 0..511
            const int row = f8 >> 3;                 // local row 0..63
            const int ch  = f8 & 7;                  // 8-float chunk
            const float* src = emb + ((ph * 64 + row) * 64 + ch * 8);
            float x[8];
            *(f32x4*)&x[0] = *(const f32x4*)(src);
            *(f32x4*)&x[4] = *(const f32x4*)(src + 4);
            bf16x8 vh, vl;
#pragma unroll
            for (int e = 0; e < 8; ++e) {
                unsigned short h = f2bf_rne(x[e]);
                vh[e] = (short)h;
                vl[e] = (short)f2bf_rne(x[e] - bf2f(h));
            }
            const int s  = ch >> 2, gg = ch & 3;
            const int tl = row >> 4, cc = row & 15;
            const int slot = (tl * 2 + s) * 64 + gg * 16 + cc;
            *(bf16x8*)(lbh + ldx(slot)) = vh;
            *(bf16x8*)(lbl + ldx(slot)) = vl;
        }
        __syncthreads();

        // 4 k-tiles, register-double-buffered one tile ahead
        bf16x8 cbh0 = *(const bf16x8*)(lbh + ldx(0 * 64 + lane));
        bf16x8 cbh1 = *(const bf16x8*)(lbh + ldx(1 * 64 + lane));
        bf16x8 cbl0 = *(const bf16x8*)(lbl + ldx(0 * 64 + lane));
        bf16x8 cbl1 = *(const bf16x8*)(lbl + ldx(1 * 64 + lane));
#pragma unroll
        for (int tl = 0; tl < 4; ++tl) {
            bf16x8 nbh0 = cbh0, nbh1 = cbh1, nbl0 = cbl0, nbl1 = cbl1;
            if (tl < 3) {
                nbh0 = *(const bf16x8*)(lbh + ldx((tl * 2 + 2) * 64 + lane));
                nbh1 = *(const bf16x8*)(lbh + ldx((tl * 2 + 3) * 64 + lane));
                nbl0 = *(const bf16x8*)(lbl + ldx((tl * 2 + 2) * 64 + lane));
                nbl1 = *(const bf16x8*)(lbl + ldx((tl * 2 + 3) * 64 + lane));
            }
            f32x4 acc0 = {0.f, 0.f, 0.f, 0.f};
            f32x4 acc1 = {0.f, 0.f, 0.f, 0.f};
            acc0 = __builtin_amdgcn_mfma_f32_16x16x32_bf16(ah[0][0], cbh0, acc0, 0, 0, 0);
            acc1 = __builtin_amdgcn_mfma_f32_16x16x32_bf16(ah[1][0], cbh0, acc1, 0, 0, 0);
            acc0 = __builtin_amdgcn_mfma_f32_16x16x32_bf16(ah[0][1], cbh1, acc0, 0, 0, 0);
            acc1 = __builtin_amdgcn_mfma_f32_16x16x32_bf16(ah[1][1], cbh1, acc1, 0, 0, 0);
            acc0 = __builtin_amdgcn_mfma_f32_16x16x32_bf16(al[0][0], cbh0, acc0, 0, 0, 0);
            acc1 = __builtin_amdgcn_mfma_f32_16x16x32_bf16(al[1][0], cbh0, acc1, 0, 0, 0);
            acc0 = __builtin_amdgcn_mfma_f32_16x16x32_bf16(al[0][1], cbh1, acc0, 0, 0, 0);
            acc1 = __builtin_amdgcn_mfma_f32_16x16x32_bf16(al[1][1], cbh1, acc1, 0, 0, 0);
            acc0 = __builtin_amdgcn_mfma_f32_16x16x32_bf16(ah[0][0], cbl0, acc0, 0, 0, 0);
            acc1 = __builtin_amdgcn_mfma_f32_16x16x32_bf16(ah[1][0], cbl0, acc1, 0, 0, 0);
            acc0 = __builtin_amdgcn_mfma_f32_16x16x32_bf16(ah[0][1], cbl1, acc0, 0, 0, 0);
            acc1 = __builtin_amdgcn_mfma_f32_16x16x32_bf16(ah[1][1], cbl1, acc1, 0, 0, 0);

            const int tg = ph * 4 + tl;
            const float ev = lesq[tg * 16 + c15];
            const int   k  = tg * 16 + c15;
#pragma unroll
            for (int r = 0; r < 4; ++r) {
                float v0 = __builtin_fmaf(-2.f, acc0[r], ev);
                bool lt0 = v0 < best[0][r];
                sec[0][r]  = lt0 ? best[0][r] : fminf(sec[0][r], v0);
                best[0][r] = lt0 ? v0 : best[0][r];
                bidx[0][r] = lt0 ? k : bidx[0][r];
                float v1 = __builtin_fmaf(-2.f, acc1[r], ev);
                bool lt1 = v1 < best[1][r];
                sec[1][r]  = lt1 ? best[1][r] : fminf(sec[1][r], v1);
                best[1][r] = lt1 ? v1 : best[1][r];
                bidx[1][r] = lt1 ? k : bidx[1][r];
            }
            cbh0 = nbh0; cbh1 = nbh1; cbl0 = nbl0; cbl1 = nbl1;
        }
    }

    // ---- butterfly-merge (best,second,idx) across the 16 cols ----
#pragma unroll
    for (int ms = 0; ms < 2; ++ms)
#pragma unroll
        for (int r = 0; r < 4; ++r) {
            float b = best[ms][r], s2 = sec[ms][r]; int bi = bidx[ms][r];
#pragma unroll
            for (int off = 1; off <= 8; off <<= 1) {
                float ob = __shfl_xor(b,  off, 64);
                float os = __shfl_xor(s2, off, 64);
                int   oi = __shfl_xor(bi, off, 64);
                bool lt = ob < b;
                float loser = lt ? b : ob;
                s2 = fminf(fminf(s2, os), loser);
                b  = lt ? ob : b;
                bi = lt ? oi : bi;
            }
            best[ms][r] = b; sec[ms][r] = s2; bidx[ms][r] = bi;
        }

    // ---- ownership: lane p (<32) owns point p = ms*16 + 4g'+r' ----
    const int srcl = 16 * ((lane & 15) >> 2);
    float bb_ = 3.4e38f, ss_ = 3.4e38f; int ii_ = 0;
#pragma unroll
    for (int ms = 0; ms < 2; ++ms)
#pragma unroll
        for (int r = 0; r < 4; ++r) {
            float gb = __shfl(best[ms][r], srcl, 64);
            float gs = __shfl(sec[ms][r],  srcl, 64);
            int   gi = __shfl(bidx[ms][r], srcl, 64);
            bool hit = (ms == (lane >> 4)) && (r == (lane & 3));
            bb_ = hit ? gb : bb_; ss_ = hit ? gs : ss_; ii_ = hit ? gi : ii_;
        }
    const bool own = lane < 32;

    // ---- adaptive margin: eps = 2*ulp(t_ub) + C, t_ub >= zsq+esq+2|dot| ----
    // Owner lane p's column is p&15 == its own lane&15, so zsq_est is local.
    const float zq   = (lane & 16) ? zsq_est[1] : zsq_est[0];
    const float t_ub = zq * 1.0001f + 0.501f;        // esq<=2.5e-4, 2|dot|<=0.4
    const float p2   = __uint_as_float((__float_as_uint(t_ub) >> 23) << 23);
    const float eps  = p2 * 2.3841858e-7f + 1.6e-5f; // 2*ulp(t_ub) + C

    // ---- ambiguous points -> compacted append to global rescue list ----
    const int m_own = mblk + wave * 32 + lane;
    unsigned long long amb = __ballot(own && (ss_ - bb_ < eps));
    const int nw = __popcll(amb);
    int base = 0;
    if (nw) {
        if (lane == 0) base = atomicAdd(cnt_p, nw);
        base = __shfl(base, 0, 64);
        if (own && (amb >> lane) & 1ull) {
            const int pos = __popcll(amb & ((1ull << lane) - 1ull));
            list[base + pos] = m_own;
        }
    }

    // ---- write provisional indices ----
    if (own)
        out[VQ_IDX_OFF + m_own] = (float)ii_;
}

// ---------------------------------------------------------------------------
// Kernel 2r: rescue. Codebook staged TRANSPOSED in LDS (lt[d][k], 128 KB —
// legal: 160 KB/CU) once per block, so rescues do ZERO L2 codebook traffic
// (R11's rescue re-read 128 KB/point from L2 -> L2-BW-bound, ~116 us).
// Block = 512 thr = 8 waves, 1 block/CU, grid 256. One WAVE per point,
// grid-strided. Read lt[d*512 + lane + 64q]: bank = lane%32 -> conflict-free.
// Bitwise reference path; lexicographic (dist,k) -> first occurrence.
// ---------------------------------------------------------------------------
__global__ __launch_bounds__(512, 1) void vq_rescue(
        const float* __restrict__ z_e,
        const float* __restrict__ emb,
        const float* __restrict__ esq,
        float* __restrict__ out,
        const int* __restrict__ cnt_p,
        const int* __restrict__ list)
{
#pragma clang fp contract(off)
    __shared__ float lt[64 * 512];               // emb^T: lt[d*512 + k]
    __shared__ float lesq[512];

    const int tid = threadIdx.x, wave = tid >> 6, lane = tid & 63;
    lesq[tid] = esq[tid];                        // 512 threads exactly
    // stage transpose: thread tid owns codebook row tid (sequential 16B
    // reads; LDS write bank = tid%32 -> 2-way = free)
#pragma unroll
    for (int i = 0; i < 16; ++i) {
        f32x4 v = *(const f32x4*)(emb + tid * 64 + i * 4);
#pragma unroll
        for (int x = 0; x < 4; ++x) lt[(i * 4 + x) * 512 + tid] = v[x];
    }
    __syncthreads();

    const int cnt = *cnt_p;
    const int nw  = gridDim.x * 8;
    for (int i = blockIdx.x * 8 + wave; i < cnt; i += nw) {
        const int m = list[i];
        const int n = m >> 12, hw = m & 4095;
        const float* zr = z_e + (size_t)n * 262144 + hw;
        float zf[64];
#pragma unroll
        for (int d = 0; d < 64; ++d) zf[d] = zr[(size_t)d * 4096];
        // zsq: numpy pairwise (bitwise)
        float r8[8];
#pragma unroll
        for (int j = 0; j < 8; ++j) r8[j] = zf[j] * zf[j];
#pragma unroll
        for (int ii = 8; ii < 64; ii += 8)
#pragma unroll
            for (int j = 0; j < 8; ++j) r8[j] += zf[ii + j] * zf[ii + j];
        const float zsq = ((r8[0] + r8[1]) + (r8[2] + r8[3]))
                        + ((r8[4] + r8[5]) + (r8[6] + r8[7]));
        // dots: lane handles k = lane + 64q, ascending-d fma chains (bitwise)
        float a[8];
#pragma unroll
        for (int q = 0; q < 8; ++q) a[q] = 0.f;
#pragma unroll
        for (int d = 0; d < 64; ++d)
#pragma unroll
            for (int q = 0; q < 8; ++q)
                a[q] = __builtin_fmaf(zf[d], lt[d * 512 + lane + 64 * q], a[q]);
        float fb = 3.4e38f; int fk = 0;
#pragma unroll
        for (int q = 0; q < 8; ++q) {            // k ascending within lane
            const int kk = lane + 64 * q;
            float tt = zsq + lesq[kk];
            float dd = tt - 2.0f * a[q];
            if (dd < fb) { fb = dd; fk = kk; }   // strict <: first occurrence
        }
#pragma unroll
        for (int off = 32; off > 0; off >>= 1) { // lexicographic (dist, k)
            float ob = __shfl_xor(fb, off, 64);
            int   ok = __shfl_xor(fk, off, 64);
            if (ob < fb || (ob == fb && ok < fk)) { fb = ob; fk = ok; }
        }
        if (lane == 0) out[VQ_IDX_OFF + m] = (float)fk;
    }
}

// ---------------------------------------------------------------------------
// Kernel 2-fallback: R9 all-in-one (inline rescue) for small workspaces.
// ---------------------------------------------------------------------------
__global__ __launch_bounds__(256, 4) void vq_main_fb(
        const float* __restrict__ z_e,
        const float* __restrict__ emb,
        const float* __restrict__ esq,
        float* __restrict__ out)
{
#pragma clang fp contract(off)
    __shared__ __align__(16) char lbh[16384];
    __shared__ __align__(16) char lbl[16384];
    __shared__ float lesq[512];

    const int tid  = threadIdx.x;
    const int wave = tid >> 6, lane = tid & 63;
    const int c15  = lane & 15, g = lane >> 4;

    lesq[tid]       = esq[tid];
    lesq[tid + 256] = esq[tid + 256];

    const int mblk = blockIdx.x * 128;
    const int n    = mblk >> 12;
    const int hwb  = (mblk & 4095) + wave * 32;
    const float* zn = z_e + (size_t)n * 262144;

    bf16x8 ah[2][2], al[2][2];
#pragma unroll
    for (int ms = 0; ms < 2; ++ms) {
        const int hw = hwb + ms * 16 + c15;
#pragma unroll
        for (int s = 0; s < 2; ++s) {
#pragma unroll
            for (int e = 0; e < 8; ++e) {
                const int d = 32 * s + 8 * g + e;
                float f = zn[(size_t)d * 4096 + hw];
                unsigned short h = f2bf_rne(f);
                ah[ms][s][e] = (short)h;
                al[ms][s][e] = (short)f2bf_rne(f - bf2f(h));
            }
        }
    }

    float best[2][4], sec[2][4];
    int   bidx[2][4];
#pragma unroll
    for (int ms = 0; ms < 2; ++ms)
#pragma unroll
        for (int r = 0; r < 4; ++r) {
            best[ms][r] = 3.4e38f; sec[ms][r] = 3.4e38f; bidx[ms][r] = 0;
        }

    for (int ph = 0; ph < 4; ++ph) {
        __syncthreads();
#pragma unroll
        for (int j = 0; j < 4; ++j) {
            const int f8  = j * 256 + tid;
            const int row = f8 >> 3;
            const int ch  = f8 & 7;
            const float* src = emb + ((ph * 128 + row) * 64 + ch * 8);
            float x[8];
            *(f32x4*)&x[0] = *(const f32x4*)(src);
            *(f32x4*)&x[4] = *(const f32x4*)(src + 4);
            bf16x8 vh, vl;
#pragma unroll
            for (int e = 0; e < 8; ++e) {
                unsigned short h = f2bf_rne(x[e]);
                vh[e] = (short)h;
                vl[e] = (short)f2bf_rne(x[e] - bf2f(h));
            }
            const int s  = ch >> 2, gg = ch & 3;
            const int tl = row >> 4, cc = row & 15;
            const int slot = (tl * 2 + s) * 64 + gg * 16 + cc;
            *(bf16x8*)(lbh + ldx(slot)) = vh;
            *(bf16x8*)(lbl + ldx(slot)) = vl;
        }
        __syncthreads();

        bf16x8 cbh0 = *(const bf16x8*)(lbh + ldx(0 * 64 + lane));
        bf16x8 cbh1 = *(const bf16x8*)(lbh + ldx(1 * 64 + lane));
        bf16x8 cbl0 = *(const bf16x8*)(lbl + ldx(0 * 64 + lane));
        bf16x8 cbl1 = *(const bf16x8*)(lbl + ldx(1 * 64 + lane));
#pragma unroll
        for (int tl = 0; tl < 8; ++tl) {
            bf16x8 nbh0 = cbh0, nbh1 = cbh1, nbl0 = cbl0, nbl1 = cbl1;
            if (tl < 7) {
                nbh0 = *(const bf16x8*)(lbh + ldx((tl * 2 + 2) * 64 + lane));
                nbh1 = *(const bf16x8*)(lbh + ldx((tl * 2 + 3) * 64 + lane));
                nbl0 = *(const bf16x8*)(lbl + ldx((tl * 2 + 2) * 64 + lane));
                nbl1 = *(const bf16x8*)(lbl + ldx((tl * 2 + 3) * 64 + lane));
            }
            f32x4 acc0 = {0.f, 0.f, 0.f, 0.f};
            f32x4 acc1 = {0.f, 0.f, 0.f, 0.f};
            acc0 = __builtin_amdgcn_mfma_f32_16x16x32_bf16(ah[0][0], cbh0, acc0, 0, 0, 0);
            acc1 = __builtin_amdgcn_mfma_f32_16x16x32_bf16(ah[1][0], cbh0, acc1, 0, 0, 0);
            acc0 = __builtin_amdgcn_mfma_f32_16x16x32_bf16(ah[0][1], cbh1, acc0, 0, 0, 0);
            acc1 = __builtin_amdgcn_mfma_f32_16x16x32_bf16(ah[1][1], cbh1, acc1, 0, 0, 0);
            acc0 = __builtin_amdgcn_mfma_f32_16x16x32_bf16(al[0][0], cbh0, acc0, 0, 0, 0);
            acc1 = __builtin_amdgcn_mfma_f32_16x16x32_bf16(al[1][0], cbh0, acc1, 0, 0, 0);
            acc0 = __builtin_amdgcn_mfma_f32_16x16x32_bf16(al[0][1], cbh1, acc0, 0, 0, 0);
            acc1 = __builtin_amdgcn_mfma_f32_16x16x32_bf16(al[1][1], cbh1, acc1, 0, 0, 0);
            acc0 = __builtin_amdgcn_mfma_f32_16x16x32_bf16(ah[0][0], cbl0, acc0, 0, 0, 0);
            acc1 = __builtin_amdgcn_mfma_f32_16x16x32_bf16(ah[1][0], cbl0, acc1, 0, 0, 0);
            acc0 = __builtin_amdgcn_mfma_f32_16x16x32_bf16(ah[0][1], cbl1, acc0, 0, 0, 0);
            acc1 = __builtin_amdgcn_mfma_f32_16x16x32_bf16(ah[1][1], cbl1, acc1, 0, 0, 0);

            const int tg = ph * 8 + tl;
            const float ev = lesq[tg * 16 + c15];
            const int   k  = tg * 16 + c15;
#pragma unroll
            for (int r = 0; r < 4; ++r) {
                float v0 = __builtin_fmaf(-2.f, acc0[r], ev);
                bool lt0 = v0 < best[0][r];
                sec[0][r]  = lt0 ? best[0][r] : fminf(sec[0][r], v0);
                best[0][r] = lt0 ? v0 : best[0][r];
                bidx[0][r] = lt0 ? k : bidx[0][r];
                float v1 = __builtin_fmaf(-2.f, acc1[r], ev);
                bool lt1 = v1 < best[1][r];
                sec[1][r]  = lt1 ? best[1][r] : fminf(sec[1][r], v1);
                best[1][r] = lt1 ? v1 : best[1][r];
                bidx[1][r] = lt1 ? k : bidx[1][r];
            }
            cbh0 = nbh0; cbh1 = nbh1; cbl0 = nbl0; cbl1 = nbl1;
        }
    }

#pragma unroll
    for (int ms = 0; ms < 2; ++ms)
#pragma unroll
        for (int r = 0; r < 4; ++r) {
            float b = best[ms][r], s2 = sec[ms][r]; int bi = bidx[ms][r];
#pragma unroll
            for (int off = 1; off <= 8; off <<= 1) {
                float ob = __shfl_xor(b,  off, 64);
                float os = __shfl_xor(s2, off, 64);
                int   oi = __shfl_xor(bi, off, 64);
                bool lt = ob < b;
                float loser = lt ? b : ob;
                s2 = fminf(fminf(s2, os), loser);
                b  = lt ? ob : b;
                bi = lt ? oi : bi;
            }
            best[ms][r] = b; sec[ms][r] = s2; bidx[ms][r] = bi;
        }

    const int srcl = 16 * ((lane & 15) >> 2);
    float bb_ = 3.4e38f, ss_ = 3.4e38f; int ii_ = 0;
#pragma unroll
    for (int ms = 0; ms < 2; ++ms)
#pragma unroll
        for (int r = 0; r < 4; ++r) {
            float gb = __shfl(best[ms][r], srcl, 64);
            float gs = __shfl(sec[ms][r],  srcl, 64);
            int   gi = __shfl(bidx[ms][r], srcl, 64);
            bool hit = (ms == (lane >> 4)) && (r == (lane & 3));
            bb_ = hit ? gb : bb_; ss_ = hit ? gs : ss_; ii_ = hit ? gi : ii_;
        }
    const bool own = lane < 32;

    unsigned long long msk = __ballot(own && (ss_ - bb_ < VQ_EPS));
    while (msk) {
        const int j = __ffsll(msk) - 1;
        msk &= msk - 1;
        const int fk = vq_exact_point(zn + hwb + j, emb, lesq, lane);
        if (lane == j) ii_ = fk;
    }

    if (own)
        out[VQ_IDX_OFF + mblk + wave * 32 + lane] = (float)ii_;
}

// ---------------------------------------------------------------------------
// Kernel 2b: epilogue. 1 thread/point, high occupancy; reads final idx.
// ---------------------------------------------------------------------------
__global__ __launch_bounds__(256, 8) void vq_epi(
        const float* __restrict__ z_e,
        const float* __restrict__ emb,
        float* __restrict__ out,
        double* __restrict__ loss_acc)
{
#pragma clang fp contract(off)
    __shared__ float wsum[4];
    const int tid  = threadIdx.x;
    const int wave = tid >> 6, lane = tid & 63;
    const int m    = blockIdx.x * 256 + tid;
    const int n    = m >> 12;
    const int hw   = m & 4095;

    const float* zp = z_e + (size_t)n * 262144 + hw;
    const int ii = (int)out[VQ_IDX_OFF + m];
    const float* eb = emb + (size_t)ii * VQ_D;
    float* op = out + (size_t)n * 262144 + hw;

    float lsum = 0.f;
#pragma unroll
    for (int c4 = 0; c4 < 16; ++c4) {
        f32x4 e4 = *(const f32x4*)(eb + c4 * 4);
#pragma unroll
        for (int x = 0; x < 4; ++x) {
            const int d = c4 * 4 + x;
            float q = e4[x];
            op[(size_t)d * 4096] = q;
            float diff = zp[(size_t)d * 4096] - q;
            lsum = __builtin_fmaf(diff, diff, lsum);
        }
    }

    for (int off = 32; off > 0; off >>= 1)
        lsum += __shfl_down(lsum, off, 64);
    if (lane == 0) wsum[wave] = lsum;
    __syncthreads();
    if (tid == 0) {
        float b = wsum[0] + wsum[1] + wsum[2] + wsum[3];
        atomicAdd(loss_acc, (double)b);
    }
}

// ---------------------------------------------------------------------------
// Kernel 3: finalize loss (mean over M*D = 16777216 elements).
// ---------------------------------------------------------------------------
__global__ void vq_fin(const double* __restrict__ loss_acc, float* __restrict__ out) {
    if (threadIdx.x == 0)
        out[VQ_LOSS_OFF] = (float)(*loss_acc / 16777216.0);
}

extern "C" void kernel_launch(void* const* d_in, const int* in_sizes, int n_in,
                              void* d_out, int out_size, void* d_ws, size_t ws_size,
                              hipStream_t stream) {
    const float* z_e = (const float*)d_in[0];
    const float* emb = (const float*)d_in[1];
    float* out = (float*)d_out;
    char* wsb = (char*)d_ws;

    double* loss_acc = (double*)wsb;

    if (ws_size >= (size_t)WS_NEED) {
        // fast path: list-based rescue with LDS-staged transposed codebook
        float* esq = (float*)(wsb + WS_ESQ_OFF);
        int*   cnt = (int*)(wsb + WS_CNT_OFF);
        int*   lst = (int*)(wsb + WS_LIST_OFF);
        (void)hipMemsetAsync(d_ws, 0, 12, stream);   // loss + cnt
        vq_prep<<<2, 256, 0, stream>>>(emb, esq);
        vq_main_fast<<<VQ_M / 128, 256, 0, stream>>>(z_e, emb, esq, out, cnt, lst);
        vq_rescue<<<256, 512, 0, stream>>>(z_e, emb, esq, out, cnt, lst);
        vq_epi<<<VQ_M / 256, 256, 0, stream>>>(z_e, emb, out, loss_acc);
        vq_fin<<<1, 64, 0, stream>>>(loss_acc, out);
    } else {
        // fallback: R9 all-in-one (proven at 310 us)
        float* esq = (float*)(wsb + 8);
        (void)hipMemsetAsync(d_ws, 0, 8, stream);
        vq_prep<<<2, 256, 0, stream>>>(emb, esq);
        vq_main_fb<<<VQ_M / 128, 256, 0, stream>>>(z_e, emb, esq, out);
        vq_epi<<<VQ_M / 256, 256, 0, stream>>>(z_e, emb, out, loss_acc);
        vq_fin<<<1, 64, 0, stream>>>(loss_acc, out);
    }
}

// Round 13
// 283.083 us; speedup vs baseline: 1.1620x; 1.1620x over previous
//
#include <hip/hip_runtime.h>

// Problem constants (N=64, D=64, H=64, W=64, K=512)
#define VQ_D   64
#define VQ_K   512
#define VQ_HW  4096
#define VQ_M   262144
#define VQ_LOSS_OFF 16777216
#define VQ_IDX_OFF  16777217

// Flat margin for the fallback path only. The fast path uses a per-point
// adaptive margin: eps = 2*ulp(t_ub) + 1.6e-5 (see vq_main_fast).
// Rescued points are recomputed with the bitwise reference path, so the
// margin affects speed only, never output.
#define VQ_EPS  1e-4f

// Fast-path workspace layout (bytes):
//   [0,8)    double loss accumulator
//   [8,12)   int rescue-list counter
//   [12,2060) float esq[512]
//   [2060, 2060+4*VQ_M) int rescue list
#define WS_CNT_OFF  8
#define WS_ESQ_OFF  12
#define WS_LIST_OFF 2060
#define WS_NEED     (2060 + 4 * VQ_M)

typedef float  f32x4  __attribute__((ext_vector_type(4)));
typedef short  bf16x8 __attribute__((ext_vector_type(8)));

__device__ __forceinline__ unsigned short f2bf_rne(float f) {
    unsigned u = __float_as_uint(f);
    u += 0x7FFFu + ((u >> 16) & 1u);
    return (unsigned short)(u >> 16);
}
__device__ __forceinline__ float bf2f(unsigned short h) {
    return __uint_as_float(((unsigned)h) << 16);
}
// LDS fragment-slot byte offset with bank swizzle (involution on write+read).
__device__ __forceinline__ int ldx(int slot) {
    return (slot << 4) ^ (((slot >> 4) & 3) << 4);
}

// ---------------------------------------------------------------------------
// Kernel 1: e_sq[k] = sum_d emb[k][d]^2 (numpy pairwise, n=64 path).
// ---------------------------------------------------------------------------
__global__ void vq_prep(const float* __restrict__ emb, float* __restrict__ esq) {
#pragma clang fp contract(off)
    int k = blockIdx.x * 256 + threadIdx.x;
    if (k < VQ_K) {
        const float* e = emb + k * VQ_D;
        float p[VQ_D];
#pragma unroll
        for (int d = 0; d < VQ_D; ++d) p[d] = e[d] * e[d];
        float r[8];
#pragma unroll
        for (int j = 0; j < 8; ++j) r[j] = p[j];
#pragma unroll
        for (int i = 8; i < VQ_D; i += 8)
#pragma unroll
            for (int j = 0; j < 8; ++j) r[j] += p[i + j];
        esq[k] = ((r[0] + r[1]) + (r[2] + r[3])) + ((r[4] + r[5]) + (r[6] + r[7]));
    }
}

// ---------------------------------------------------------------------------
// Shared device helper (fallback path): wave-cooperative EXACT argmin,
// codebook from L2. Bitwise reference path; lexicographic (dist,k) reduce.
// ---------------------------------------------------------------------------
__device__ __forceinline__ int vq_exact_point(
        const float* __restrict__ zr,      // wave-uniform &z[n][0][hw]
        const float* __restrict__ emb,
        const float* __restrict__ esq,     // any source w/ identical bits
        int lane)
{
    float r8[8];
#pragma unroll
    for (int dj = 0; dj < 8; ++dj) {
        float f = zr[(size_t)dj * 4096];
        r8[dj] = f * f;
    }
#pragma unroll
    for (int i = 8; i < 64; i += 8)
#pragma unroll
        for (int dj = 0; dj < 8; ++dj) {
            float f = zr[(size_t)(i + dj) * 4096];
            r8[dj] += f * f;
        }
    const float zsq = ((r8[0] + r8[1]) + (r8[2] + r8[3]))
                    + ((r8[4] + r8[5]) + (r8[6] + r8[7]));
    float a[8];
#pragma unroll
    for (int q = 0; q < 8; ++q) a[q] = 0.f;
    const float* er0 = emb + (size_t)(lane * 8) * VQ_D;
    for (int c4 = 0; c4 < 16; ++c4) {
        f32x4 z4;
#pragma unroll
        for (int x = 0; x < 4; ++x) z4[x] = zr[(size_t)(c4 * 4 + x) * 4096];
#pragma unroll
        for (int q = 0; q < 8; ++q) {
            f32x4 e4 = *(const f32x4*)(er0 + q * VQ_D + c4 * 4);
#pragma unroll
            for (int x = 0; x < 4; ++x)
                a[q] = __builtin_fmaf(z4[x], e4[x], a[q]);
        }
    }
    float fb = 3.4e38f; int fk = 0;
#pragma unroll
    for (int q = 0; q < 8; ++q) {                // k ascending within lane
        const int kk = lane * 8 + q;
        float tt = zsq + esq[kk];
        float dd = tt - 2.0f * a[q];
        if (dd < fb) { fb = dd; fk = kk; }       // strict <: first occurrence
    }
#pragma unroll
    for (int off = 32; off > 0; off >>= 1) {     // lexicographic (dist, k)
        float ob = __shfl_xor(fb, off, 64);
        int   ok = __shfl_xor(fk, off, 64);
        if (ob < fb || (ob == fb && ok < fk)) { fb = ob; fk = ok; }
    }
    return fk;
}

// ---------------------------------------------------------------------------
// Kernel 2 (fast path): MFMA argmin, provisional idx + ambiguous-list
// append with PER-POINT adaptive margin. Uniform block duration (no inline
// rescue). 8 LDS phases x 64 rows (18.4 KB); launch_bounds(256,4) -> VGPR
// ~66, no spills.
// ---------------------------------------------------------------------------
__global__ __launch_bounds__(256, 4) void vq_main_fast(
        const float* __restrict__ z_e,
        const float* __restrict__ emb,
        const float* __restrict__ esq,
        float* __restrict__ out,
        int* __restrict__ cnt_p,
        int* __restrict__ list)
{
#pragma clang fp contract(off)
    __shared__ __align__(16) char lbh[8192];    // one phase (64 rows), hi
    __shared__ __align__(16) char lbl[8192];    // one phase, lo
    __shared__ float lesq[512];

    const int tid  = threadIdx.x;
    const int wave = tid >> 6, lane = tid & 63;
    const int c15  = lane & 15, g = lane >> 4;

    lesq[tid]       = esq[tid];
    lesq[tid + 256] = esq[tid + 256];

    const int mblk = blockIdx.x * 128;               // block's first point
    const int n    = mblk >> 12;                     // all 128 pts in one n
    const int hwb  = (mblk & 4095) + wave * 32;      // wave's first hw
    const float* zn = z_e + (size_t)n * 262144;

    // ---- A fragments: z hi/lo for 2 m-subtiles x 2 k-halves, plus a
    //      per-point zsq upper-bound estimate (for the adaptive margin) ----
    bf16x8 ah[2][2], al[2][2];
    float zsq_est[2];
#pragma unroll
    for (int ms = 0; ms < 2; ++ms) {
        const int hw = hwb + ms * 16 + c15;
        float sq = 0.f;
#pragma unroll
        for (int s = 0; s < 2; ++s) {
#pragma unroll
            for (int e = 0; e < 8; ++e) {
                const int d = 32 * s + 8 * g + e;
                float f = zn[(size_t)d * 4096 + hw];
                sq = __builtin_fmaf(f, f, sq);
                unsigned short h = f2bf_rne(f);
                ah[ms][s][e] = (short)h;
                al[ms][s][e] = (short)f2bf_rne(f - bf2f(h));
            }
        }
        sq += __shfl_xor(sq, 16, 64);                // reduce over g
        sq += __shfl_xor(sq, 32, 64);
        zsq_est[ms] = sq;                            // all g-lanes of col c15
    }

    float best[2][4], sec[2][4];
    int   bidx[2][4];
#pragma unroll
    for (int ms = 0; ms < 2; ++ms)
#pragma unroll
        for (int r = 0; r < 4; ++r) {
            best[ms][r] = 3.4e38f; sec[ms][r] = 3.4e38f; bidx[ms][r] = 0;
        }

    // ---- scan K in eight LDS phases of 64 rows ----
    for (int ph = 0; ph < 8; ++ph) {
        __syncthreads();                             // prior readers done
#pragma unroll
        for (int j = 0; j < 2; ++j) {
            const int f8  = j * 256 + tid;           // 0..511
            const int row = f8 >> 3;                 // local row 0..63
            const int ch  = f8 & 7;                  // 8-float chunk
            const float* src = emb + ((ph * 64 + row) * 64 + ch * 8);
            float x[8];
            *(f32x4*)&x[0] = *(const f32x4*)(src);
            *(f32x4*)&x[4] = *(const f32x4*)(src + 4);
            bf16x8 vh, vl;
#pragma unroll
            for (int e = 0; e < 8; ++e) {
                unsigned short h = f2bf_rne(x[e]);
                vh[e] = (short)h;
                vl[e] = (short)f2bf_rne(x[e] - bf2f(h));
            }
            const int s  = ch >> 2, gg = ch & 3;
            const int tl = row >> 4, cc = row & 15;
            const int slot = (tl * 2 + s) * 64 + gg * 16 + cc;
            *(bf16x8*)(lbh + ldx(slot)) = vh;
            *(bf16x8*)(lbl + ldx(slot)) = vl;
        }
        __syncthreads();

        // 4 k-tiles, register-double-buffered one tile ahead
        bf16x8 cbh0 = *(const bf16x8*)(lbh + ldx(0 * 64 + lane));
        bf16x8 cbh1 = *(const bf16x8*)(lbh + ldx(1 * 64 + lane));
        bf16x8 cbl0 = *(const bf16x8*)(lbl + ldx(0 * 64 + lane));
        bf16x8 cbl1 = *(const bf16x8*)(lbl + ldx(1 * 64 + lane));
#pragma unroll
        for (int tl = 0; tl < 4; ++tl) {
            bf16x8 nbh0 = cbh0, nbh1 = cbh1, nbl0 = cbl0, nbl1 = cbl1;
            if (tl < 3) {
                nbh0 = *(const bf16x8*)(lbh + ldx((tl * 2 + 2) * 64 + lane));
                nbh1 = *(const bf16x8*)(lbh + ldx((tl * 2 + 3) * 64 + lane));
                nbl0 = *(const bf16x8*)(lbl + ldx((tl * 2 + 2) * 64 + lane));
                nbl1 = *(const bf16x8*)(lbl + ldx((tl * 2 + 3) * 64 + lane));
            }
            f32x4 acc0 = {0.f, 0.f, 0.f, 0.f};
            f32x4 acc1 = {0.f, 0.f, 0.f, 0.f};
            acc0 = __builtin_amdgcn_mfma_f32_16x16x32_bf16(ah[0][0], cbh0, acc0, 0, 0, 0);
            acc1 = __builtin_amdgcn_mfma_f32_16x16x32_bf16(ah[1][0], cbh0, acc1, 0, 0, 0);
            acc0 = __builtin_amdgcn_mfma_f32_16x16x32_bf16(ah[0][1], cbh1, acc0, 0, 0, 0);
            acc1 = __builtin_amdgcn_mfma_f32_16x16x32_bf16(ah[1][1], cbh1, acc1, 0, 0, 0);
            acc0 = __builtin_amdgcn_mfma_f32_16x16x32_bf16(al[0][0], cbh0, acc0, 0, 0, 0);
            acc1 = __builtin_amdgcn_mfma_f32_16x16x32_bf16(al[1][0], cbh0, acc1, 0, 0, 0);
            acc0 = __builtin_amdgcn_mfma_f32_16x16x32_bf16(al[0][1], cbh1, acc0, 0, 0, 0);
            acc1 = __builtin_amdgcn_mfma_f32_16x16x32_bf16(al[1][1], cbh1, acc1, 0, 0, 0);
            acc0 = __builtin_amdgcn_mfma_f32_16x16x32_bf16(ah[0][0], cbl0, acc0, 0, 0, 0);
            acc1 = __builtin_amdgcn_mfma_f32_16x16x32_bf16(ah[1][0], cbl0, acc1, 0, 0, 0);
            acc0 = __builtin_amdgcn_mfma_f32_16x16x32_bf16(ah[0][1], cbl1, acc0, 0, 0, 0);
            acc1 = __builtin_amdgcn_mfma_f32_16x16x32_bf16(ah[1][1], cbl1, acc1, 0, 0, 0);

            const int tg = ph * 4 + tl;
            const float ev = lesq[tg * 16 + c15];
            const int   k  = tg * 16 + c15;
#pragma unroll
            for (int r = 0; r < 4; ++r) {
                float v0 = __builtin_fmaf(-2.f, acc0[r], ev);
                bool lt0 = v0 < best[0][r];
                sec[0][r]  = lt0 ? best[0][r] : fminf(sec[0][r], v0);
                best[0][r] = lt0 ? v0 : best[0][r];
                bidx[0][r] = lt0 ? k : bidx[0][r];
                float v1 = __builtin_fmaf(-2.f, acc1[r], ev);
                bool lt1 = v1 < best[1][r];
                sec[1][r]  = lt1 ? best[1][r] : fminf(sec[1][r], v1);
                best[1][r] = lt1 ? v1 : best[1][r];
                bidx[1][r] = lt1 ? k : bidx[1][r];
            }
            cbh0 = nbh0; cbh1 = nbh1; cbl0 = nbl0; cbl1 = nbl1;
        }
    }

    // ---- butterfly-merge (best,second,idx) across the 16 cols ----
#pragma unroll
    for (int ms = 0; ms < 2; ++ms)
#pragma unroll
        for (int r = 0; r < 4; ++r) {
            float b = best[ms][r], s2 = sec[ms][r]; int bi = bidx[ms][r];
#pragma unroll
            for (int off = 1; off <= 8; off <<= 1) {
                float ob = __shfl_xor(b,  off, 64);
                float os = __shfl_xor(s2, off, 64);
                int   oi = __shfl_xor(bi, off, 64);
                bool lt = ob < b;
                float loser = lt ? b : ob;
                s2 = fminf(fminf(s2, os), loser);
                b  = lt ? ob : b;
                bi = lt ? oi : bi;
            }
            best[ms][r] = b; sec[ms][r] = s2; bidx[ms][r] = bi;
        }

    // ---- ownership: lane p (<32) owns point p = ms*16 + 4g'+r' ----
    const int srcl = 16 * ((lane & 15) >> 2);
    float bb_ = 3.4e38f, ss_ = 3.4e38f; int ii_ = 0;
#pragma unroll
    for (int ms = 0; ms < 2; ++ms)
#pragma unroll
        for (int r = 0; r < 4; ++r) {
            float gb = __shfl(best[ms][r], srcl, 64);
            float gs = __shfl(sec[ms][r],  srcl, 64);
            int   gi = __shfl(bidx[ms][r], srcl, 64);
            bool hit = (ms == (lane >> 4)) && (r == (lane & 3));
            bb_ = hit ? gb : bb_; ss_ = hit ? gs : ss_; ii_ = hit ? gi : ii_;
        }
    const bool own = lane < 32;

    // ---- adaptive margin: eps = 2*ulp(t_ub) + C, t_ub >= zsq+esq+2|dot| ----
    const float zq   = (lane & 16) ? zsq_est[1] : zsq_est[0];
    const float t_ub = zq * 1.0001f + 0.501f;        // esq<=2.5e-4, 2|dot|<=0.4
    const float p2   = __uint_as_float((__float_as_uint(t_ub) >> 23) << 23);
    const float eps  = p2 * 2.3841858e-7f + 1.6e-5f; // 2*ulp(t_ub) + C

    // ---- ambiguous points -> compacted append to global rescue list ----
    const int m_own = mblk + wave * 32 + lane;
    unsigned long long amb = __ballot(own && (ss_ - bb_ < eps));
    const int nw = __popcll(amb);
    int base = 0;
    if (nw) {
        if (lane == 0) base = atomicAdd(cnt_p, nw);
        base = __shfl(base, 0, 64);
        if (own && (amb >> lane) & 1ull) {
            const int pos = __popcll(amb & ((1ull << lane) - 1ull));
            list[base + pos] = m_own;
        }
    }

    // ---- write provisional indices ----
    if (own)
        out[VQ_IDX_OFF + m_own] = (float)ii_;
}

// ---------------------------------------------------------------------------
// Kernel 2r: rescue. Codebook staged TRANSPOSED in LDS (lt[d][k], 128 KB)
// once per block (zero L2 codebook traffic). R12's version spilled zf[64]
// to scratch (107 MB WRITE, 116 us); this version is spill-proof:
//  - d-blocked z streaming: 8 current + 8 prefetch regs, blocks ascending
//    so every fma chain keeps the reference's ascending-d order bitwise.
//  - lane -> k in {4L..4L+3} u {256+4L..256+4L+3}: each (d,half) dot read
//    is one lane-consecutive ds_read_b128 (conflict-free), 128 reads/point
//    instead of 512 scalar b32.
// Block = 512 thr = 8 waves, 1 block/CU, grid 256; one WAVE per point,
// grid-strided. Bitwise reference path; lexicographic (dist,k) reduce.
// ---------------------------------------------------------------------------
__global__ __launch_bounds__(512, 1) void vq_rescue(
        const float* __restrict__ z_e,
        const float* __restrict__ emb,
        const float* __restrict__ esq,
        float* __restrict__ out,
        const int* __restrict__ cnt_p,
        const int* __restrict__ list)
{
#pragma clang fp contract(off)
    __shared__ float lt[64 * 512];               // emb^T: lt[d*512 + k]
    __shared__ float lesq[512];

    const int tid = threadIdx.x, wave = tid >> 6, lane = tid & 63;
    lesq[tid] = esq[tid];                        // 512 threads exactly
    // stage transpose: thread tid owns codebook row k=tid (sequential 16B
    // reads; LDS write: consecutive tid -> consecutive 4B -> conflict-free)
#pragma unroll
    for (int i = 0; i < 16; ++i) {
        f32x4 v = *(const f32x4*)(emb + tid * 64 + i * 4);
#pragma unroll
        for (int x = 0; x < 4; ++x) lt[(i * 4 + x) * 512 + tid] = v[x];
    }
    __syncthreads();

    const int cnt = *cnt_p;
    const int nwv = gridDim.x * 8;
    for (int i = blockIdx.x * 8 + wave; i < cnt; i += nwv) {
        const int m = list[i];
        const int n = m >> 12, hw = m & 4095;
        const float* zr = z_e + (size_t)n * 262144 + hw;

        float a[8];
#pragma unroll
        for (int q = 0; q < 8; ++q) a[q] = 0.f;
        float r8[8];

        // d-blocked stream with 1-block prefetch (16 z regs live, no spill)
        float zc[8], zp[8];
#pragma unroll
        for (int j = 0; j < 8; ++j) zc[j] = zr[(size_t)j * 4096];
#pragma unroll
        for (int db = 0; db < 64; db += 8) {
            if (db < 56) {
#pragma unroll
                for (int j = 0; j < 8; ++j)
                    zp[j] = zr[(size_t)(db + 8 + j) * 4096];
            }
            // zsq accumulation: numpy pairwise n=64 pattern (bitwise)
#pragma unroll
            for (int j = 0; j < 8; ++j) {
                float pp = zc[j] * zc[j];
                if (db == 0) r8[j] = pp; else r8[j] += pp;
            }
            // dots: per d, two lane-consecutive b128 reads cover this
            // lane's 8 k's; fma chains ascend in d (bitwise ref order)
#pragma unroll
            for (int j = 0; j < 8; ++j) {
                const int d = db + j;
                f32x4 e0 = *(const f32x4*)&lt[d * 512 + 4 * lane];
                f32x4 e1 = *(const f32x4*)&lt[d * 512 + 256 + 4 * lane];
#pragma unroll
                for (int x = 0; x < 4; ++x) {
                    a[x]     = __builtin_fmaf(zc[j], e0[x], a[x]);
                    a[4 + x] = __builtin_fmaf(zc[j], e1[x], a[4 + x]);
                }
            }
#pragma unroll
            for (int j = 0; j < 8; ++j) zc[j] = zp[j];
        }
        const float zsq = ((r8[0] + r8[1]) + (r8[2] + r8[3]))
                        + ((r8[4] + r8[5]) + (r8[6] + r8[7]));

        float fb = 3.4e38f; int fk = 0;
#pragma unroll
        for (int q = 0; q < 8; ++q) {            // k ascending within lane
            const int kk = (q < 4) ? (4 * lane + q) : (256 + 4 * lane + q - 4);
            float tt = zsq + lesq[kk];
            float dd = tt - 2.0f * a[q];
            if (dd < fb) { fb = dd; fk = kk; }   // strict <: first occurrence
        }
#pragma unroll
        for (int off = 32; off > 0; off >>= 1) { // lexicographic (dist, k)
            float ob = __shfl_xor(fb, off, 64);
            int   ok = __shfl_xor(fk, off, 64);
            if (ob < fb || (ob == fb && ok < fk)) { fb = ob; fk = ok; }
        }
        if (lane == 0) out[VQ_IDX_OFF + m] = (float)fk;
    }
}

// ---------------------------------------------------------------------------
// Kernel 2-fallback: R9 all-in-one (inline rescue) for small workspaces.
// ---------------------------------------------------------------------------
__global__ __launch_bounds__(256, 4) void vq_main_fb(
        const float* __restrict__ z_e,
        const float* __restrict__ emb,
        const float* __restrict__ esq,
        float* __restrict__ out)
{
#pragma clang fp contract(off)
    __shared__ __align__(16) char lbh[16384];
    __shared__ __align__(16) char lbl[16384];
    __shared__ float lesq[512];

    const int tid  = threadIdx.x;
    const int wave = tid >> 6, lane = tid & 63;
    const int c15  = lane & 15, g = lane >> 4;

    lesq[tid]       = esq[tid];
    lesq[tid + 256] = esq[tid + 256];

    const int mblk = blockIdx.x * 128;
    const int n    = mblk >> 12;
    const int hwb  = (mblk & 4095) + wave * 32;
    const float* zn = z_e + (size_t)n * 262144;

    bf16x8 ah[2][2], al[2][2];
#pragma unroll
    for (int ms = 0; ms < 2; ++ms) {
        const int hw = hwb + ms * 16 + c15;
#pragma unroll
        for (int s = 0; s < 2; ++s) {
#pragma unroll
            for (int e = 0; e < 8; ++e) {
                const int d = 32 * s + 8 * g + e;
                float f = zn[(size_t)d * 4096 + hw];
                unsigned short h = f2bf_rne(f);
                ah[ms][s][e] = (short)h;
                al[ms][s][e] = (short)f2bf_rne(f - bf2f(h));
            }
        }
    }

    float best[2][4], sec[2][4];
    int   bidx[2][4];
#pragma unroll
    for (int ms = 0; ms < 2; ++ms)
#pragma unroll
        for (int r = 0; r < 4; ++r) {
            best[ms][r] = 3.4e38f; sec[ms][r] = 3.4e38f; bidx[ms][r] = 0;
        }

    for (int ph = 0; ph < 4; ++ph) {
        __syncthreads();
#pragma unroll
        for (int j = 0; j < 4; ++j) {
            const int f8  = j * 256 + tid;
            const int row = f8 >> 3;
            const int ch  = f8 & 7;
            const float* src = emb + ((ph * 128 + row) * 64 + ch * 8);
            float x[8];
            *(f32x4*)&x[0] = *(const f32x4*)(src);
            *(f32x4*)&x[4] = *(const f32x4*)(src + 4);
            bf16x8 vh, vl;
#pragma unroll
            for (int e = 0; e < 8; ++e) {
                unsigned short h = f2bf_rne(x[e]);
                vh[e] = (short)h;
                vl[e] = (short)f2bf_rne(x[e] - bf2f(h));
            }
            const int s  = ch >> 2, gg = ch & 3;
            const int tl = row >> 4, cc = row & 15;
            const int slot = (tl * 2 + s) * 64 + gg * 16 + cc;
            *(bf16x8*)(lbh + ldx(slot)) = vh;
            *(bf16x8*)(lbl + ldx(slot)) = vl;
        }
        __syncthreads();

        bf16x8 cbh0 = *(const bf16x8*)(lbh + ldx(0 * 64 + lane));
        bf16x8 cbh1 = *(const bf16x8*)(lbh + ldx(1 * 64 + lane));
        bf16x8 cbl0 = *(const bf16x8*)(lbl + ldx(0 * 64 + lane));
        bf16x8 cbl1 = *(const bf16x8*)(lbl + ldx(1 * 64 + lane));
#pragma unroll
        for (int tl = 0; tl < 8; ++tl) {
            bf16x8 nbh0 = cbh0, nbh1 = cbh1, nbl0 = cbl0, nbl1 = cbl1;
            if (tl < 7) {
                nbh0 = *(const bf16x8*)(lbh + ldx((tl * 2 + 2) * 64 + lane));
                nbh1 = *(const bf16x8*)(lbh + ldx((tl * 2 + 3) * 64 + lane));
                nbl0 = *(const bf16x8*)(lbl + ldx((tl * 2 + 2) * 64 + lane));
                nbl1 = *(const bf16x8*)(lbl + ldx((tl * 2 + 3) * 64 + lane));
            }
            f32x4 acc0 = {0.f, 0.f, 0.f, 0.f};
            f32x4 acc1 = {0.f, 0.f, 0.f, 0.f};
            acc0 = __builtin_amdgcn_mfma_f32_16x16x32_bf16(ah[0][0], cbh0, acc0, 0, 0, 0);
            acc1 = __builtin_amdgcn_mfma_f32_16x16x32_bf16(ah[1][0], cbh0, acc1, 0, 0, 0);
            acc0 = __builtin_amdgcn_mfma_f32_16x16x32_bf16(ah[0][1], cbh1, acc0, 0, 0, 0);
            acc1 = __builtin_amdgcn_mfma_f32_16x16x32_bf16(ah[1][1], cbh1, acc1, 0, 0, 0);
            acc0 = __builtin_amdgcn_mfma_f32_16x16x32_bf16(al[0][0], cbh0, acc0, 0, 0, 0);
            acc1 = __builtin_amdgcn_mfma_f32_16x16x32_bf16(al[1][0], cbh0, acc1, 0, 0, 0);
            acc0 = __builtin_amdgcn_mfma_f32_16x16x32_bf16(al[0][1], cbh1, acc0, 0, 0, 0);
            acc1 = __builtin_amdgcn_mfma_f32_16x16x32_bf16(al[1][1], cbh1, acc1, 0, 0, 0);
            acc0 = __builtin_amdgcn_mfma_f32_16x16x32_bf16(ah[0][0], cbl0, acc0, 0, 0, 0);
            acc1 = __builtin_amdgcn_mfma_f32_16x16x32_bf16(ah[1][0], cbl0, acc1, 0, 0, 0);
            acc0 = __builtin_amdgcn_mfma_f32_16x16x32_bf16(ah[0][1], cbl1, acc0, 0, 0, 0);
            acc1 = __builtin_amdgcn_mfma_f32_16x16x32_bf16(ah[1][1], cbl1, acc1, 0, 0, 0);

            const int tg = ph * 8 + tl;
            const float ev = lesq[tg * 16 + c15];
            const int   k  = tg * 16 + c15;
#pragma unroll
            for (int r = 0; r < 4; ++r) {
                float v0 = __builtin_fmaf(-2.f, acc0[r], ev);
                bool lt0 = v0 < best[0][r];
                sec[0][r]  = lt0 ? best[0][r] : fminf(sec[0][r], v0);
                best[0][r] = lt0 ? v0 : best[0][r];
                bidx[0][r] = lt0 ? k : bidx[0][r];
                float v1 = __builtin_fmaf(-2.f, acc1[r], ev);
                bool lt1 = v1 < best[1][r];
                sec[1][r]  = lt1 ? best[1][r] : fminf(sec[1][r], v1);
                best[1][r] = lt1 ? v1 : best[1][r];
                bidx[1][r] = lt1 ? k : bidx[1][r];
            }
            cbh0 = nbh0; cbh1 = nbh1; cbl0 = nbl0; cbl1 = nbl1;
        }
    }

#pragma unroll
    for (int ms = 0; ms < 2; ++ms)
#pragma unroll
        for (int r = 0; r < 4; ++r) {
            float b = best[ms][r], s2 = sec[ms][r]; int bi = bidx[ms][r];
#pragma unroll
            for (int off = 1; off <= 8; off <<= 1) {
                float ob = __shfl_xor(b,  off, 64);
                float os = __shfl_xor(s2, off, 64);
                int   oi = __shfl_xor(bi, off, 64);
                bool lt = ob < b;
                float loser = lt ? b : ob;
                s2 = fminf(fminf(s2, os), loser);
                b  = lt ? ob : b;
                bi = lt ? oi : bi;
            }
            best[ms][r] = b; sec[ms][r] = s2; bidx[ms][r] = bi;
        }

    const int srcl = 16 * ((lane & 15) >> 2);
    float bb_ = 3.4e38f, ss_ = 3.4e38f; int ii_ = 0;
#pragma unroll
    for (int ms = 0; ms < 2; ++ms)
#pragma unroll
        for (int r = 0; r < 4; ++r) {
            float gb = __shfl(best[ms][r], srcl, 64);
            float gs = __shfl(sec[ms][r],  srcl, 64);
            int   gi = __shfl(bidx[ms][r], srcl, 64);
            bool hit = (ms == (lane >> 4)) && (r == (lane & 3));
            bb_ = hit ? gb : bb_; ss_ = hit ? gs : ss_; ii_ = hit ? gi : ii_;
        }
    const bool own = lane < 32;

    unsigned long long msk = __ballot(own && (ss_ - bb_ < VQ_EPS));
    while (msk) {
        const int j = __ffsll(msk) - 1;
        msk &= msk - 1;
        const int fk = vq_exact_point(zn + hwb + j, emb, lesq, lane);
        if (lane == j) ii_ = fk;
    }

    if (own)
        out[VQ_IDX_OFF + mblk + wave * 32 + lane] = (float)ii_;
}

// ---------------------------------------------------------------------------
// Kernel 2b: epilogue. 1 thread/point, high occupancy; reads final idx.
// ---------------------------------------------------------------------------
__global__ __launch_bounds__(256, 8) void vq_epi(
        const float* __restrict__ z_e,
        const float* __restrict__ emb,
        float* __restrict__ out,
        double* __restrict__ loss_acc)
{
#pragma clang fp contract(off)
    __shared__ float wsum[4];
    const int tid  = threadIdx.x;
    const int wave = tid >> 6, lane = tid & 63;
    const int m    = blockIdx.x * 256 + tid;
    const int n    = m >> 12;
    const int hw   = m & 4095;

    const float* zp = z_e + (size_t)n * 262144 + hw;
    const int ii = (int)out[VQ_IDX_OFF + m];
    const float* eb = emb + (size_t)ii * VQ_D;
    float* op = out + (size_t)n * 262144 + hw;

    float lsum = 0.f;
#pragma unroll
    for (int c4 = 0; c4 < 16; ++c4) {
        f32x4 e4 = *(const f32x4*)(eb + c4 * 4);
#pragma unroll
        for (int x = 0; x < 4; ++x) {
            const int d = c4 * 4 + x;
            float q = e4[x];
            op[(size_t)d * 4096] = q;
            float diff = zp[(size_t)d * 4096] - q;
            lsum = __builtin_fmaf(diff, diff, lsum);
        }
    }

    for (int off = 32; off > 0; off >>= 1)
        lsum += __shfl_down(lsum, off, 64);
    if (lane == 0) wsum[wave] = lsum;
    __syncthreads();
    if (tid == 0) {
        float b = wsum[0] + wsum[1] + wsum[2] + wsum[3];
        atomicAdd(loss_acc, (double)b);
    }
}

// ---------------------------------------------------------------------------
// Kernel 3: finalize loss (mean over M*D = 16777216 elements).
// ---------------------------------------------------------------------------
__global__ void vq_fin(const double* __restrict__ loss_acc, float* __restrict__ out) {
    if (threadIdx.x == 0)
        out[VQ_LOSS_OFF] = (float)(*loss_acc / 16777216.0);
}

extern "C" void kernel_launch(void* const* d_in, const int* in_sizes, int n_in,
                              void* d_out, int out_size, void* d_ws, size_t ws_size,
                              hipStream_t stream) {
    const float* z_e = (const float*)d_in[0];
    const float* emb = (const float*)d_in[1];
    float* out = (float*)d_out;
    char* wsb = (char*)d_ws;

    double* loss_acc = (double*)wsb;

    if (ws_size >= (size_t)WS_NEED) {
        // fast path: list-based rescue with LDS-staged transposed codebook
        float* esq = (float*)(wsb + WS_ESQ_OFF);
        int*   cnt = (int*)(wsb + WS_CNT_OFF);
        int*   lst = (int*)(wsb + WS_LIST_OFF);
        (void)hipMemsetAsync(d_ws, 0, 12, stream);   // loss + cnt
        vq_prep<<<2, 256, 0, stream>>>(emb, esq);
        vq_main_fast<<<VQ_M / 128, 256, 0, stream>>>(z_e, emb, esq, out, cnt, lst);
        vq_rescue<<<256, 512, 0, stream>>>(z_e, emb, esq, out, cnt, lst);
        vq_epi<<<VQ_M / 256, 256, 0, stream>>>(z_e, emb, out, loss_acc);
        vq_fin<<<1, 64, 0, stream>>>(loss_acc, out);
    } else {
        // fallback: R9 all-in-one (proven at 310 us)
        float* esq = (float*)(wsb + 8);
        (void)hipMemsetAsync(d_ws, 0, 8, stream);
        vq_prep<<<2, 256, 0, stream>>>(emb, esq);
        vq_main_fb<<<VQ_M / 128, 256, 0, stream>>>(z_e, emb, esq, out);
        vq_epi<<<VQ_M / 256, 256, 0, stream>>>(z_e, emb, out, loss_acc);
        vq_fin<<<1, 64, 0, stream>>>(loss_acc, out);
    }
}